// Round 14
// baseline (70.819 us; speedup 1.0000x reference)
//
#include <hip/hip_runtime.h>

#define BATCH 4
#define NPTS 4096
#define DF 64
#define ITILE 256              // 8 row-groups x 32 rows (x2 j-half wave groups)
#define JSPLIT 8
#define JCH (NPTS/JSPLIT)      // 512
#define JHALF (JCH/2)          // 256 per j-half wave group
#define JT 32
#define NT (JHALF/JT)          // 8
#define AUGD 96                // 80 feature (5x K16) + 16 spatial (1x K16)
#define LOG2E 1.4426950408889634f

typedef short short8 __attribute__((ext_vector_type(8)));
typedef float f32x16 __attribute__((ext_vector_type(16)));

__device__ __forceinline__ unsigned short bfb(float x){
  unsigned int u = __float_as_uint(x);
  u += 0x7FFFu + ((u>>16)&1u);          // RNE
  return (unsigned short)(u>>16);
}
__device__ __forceinline__ float bff(unsigned short h){
  return __uint_as_float(((unsigned int)h)<<16);
}
__device__ __forceinline__ float fexp2(float x){   // raw v_exp_f32 (2^x)
  float r; asm("v_exp_f32 %0, %1" : "=v"(r) : "v"(x)); return r;
}

// ---------------------------------------------------------------- prepass ---
// UNCHANGED from R12/R13 (validated, absmax 0.0). Scores in log2 domain,
// fully folded into the MFMA:
//  accF = log2e*(2*f1.f2 - |f2|^2)
//  accS = log2e*(2*xs_i.xs_j - |xs_j|^2) - bf16(log2e*|xs_i|^2)
__global__ void df_prep(const float* __restrict__ pts,
                        const float* __restrict__ f1,
                        const float* __restrict__ f2,
                        unsigned short* __restrict__ augI,
                        unsigned short* __restrict__ augJ)
{
  int wid = (blockIdx.x<<2) + (threadIdx.x>>6);
  int lane = threadIdx.x & 63;
  if (wid >= BATCH*NPTS) return;
  float v1 = f1[(size_t)wid*DF + lane];
  float v2 = f2[(size_t)wid*DF + lane];
  float r2 = v2*v2;
  #pragma unroll
  for (int s=32;s>=1;s>>=1)
    r2 += __shfl_xor(r2, s);
  augI[(size_t)wid*AUGD + lane] = bfb(2.0f*LOG2E*v1);
  augJ[(size_t)wid*AUGD + lane] = bfb(v2);
  if (lane==0){
    float px = pts[(size_t)wid*3+0]/0.05f;
    float py = pts[(size_t)wid*3+1]/0.05f;
    float pz = pts[(size_t)wid*3+2]/0.05f;
    float nss = px*px+py*py+pz*pz;
    unsigned short* tI = augI + (size_t)wid*AUGD;
    unsigned short* tJ = augJ + (size_t)wid*AUGD;
    float fn = LOG2E*r2;
    unsigned short a0 = bfb(fn); float rem = fn - bff(a0);
    unsigned short a1 = bfb(rem); rem -= bff(a1);
    unsigned short a2 = bfb(rem);
    tJ[64]=a0; tJ[65]=a1; tJ[66]=a2;
    #pragma unroll
    for (int k=67;k<80;k++) tJ[k]=0;
    unsigned short hx=bfb(px), hy=bfb(py), hz=bfb(pz);
    float lx = px-bff(hx), ly = py-bff(hy), lz = pz-bff(hz);
    unsigned short lxb=bfb(lx), lyb=bfb(ly), lzb=bfb(lz);
    tJ[80]=hx; tJ[81]=hy; tJ[82]=hz;
    tJ[83]=lxb;tJ[84]=lyb;tJ[85]=lzb;
    tJ[86]=hx; tJ[87]=hy; tJ[88]=hz;
    tJ[89]=lxb;tJ[90]=lyb;tJ[91]=lzb;
    float sn = LOG2E*nss;
    a0 = bfb(sn); rem = sn - bff(a0);
    a1 = bfb(rem); rem -= bff(a1);
    a2 = bfb(rem);
    tJ[92]=a0; tJ[93]=a1; tJ[94]=a2;
    tJ[95]=bfb(1.0f);                    // exact 1.0: carries -sn_i shift
    unsigned short mone = bfb(-1.0f);
    tI[64]=mone; tI[65]=mone; tI[66]=mone;
    #pragma unroll
    for (int k=67;k<80;k++) tI[k]=0;
    float sx = 2.f*LOG2E*px, sy = 2.f*LOG2E*py, sz = 2.f*LOG2E*pz;
    unsigned short h2x=bfb(sx), h2y=bfb(sy), h2z=bfb(sz);
    float l2xf = sx-bff(h2x), l2yf = sy-bff(h2y), l2zf = sz-bff(h2z);
    unsigned short l2x=bfb(l2xf), l2y=bfb(l2yf), l2z=bfb(l2zf);
    tI[80]=h2x; tI[81]=h2y; tI[82]=h2z;
    tI[83]=h2x; tI[84]=h2y; tI[85]=h2z;
    tI[86]=l2x; tI[87]=l2y; tI[88]=l2z;
    tI[89]=l2x; tI[90]=l2y; tI[91]=l2z;
    tI[92]=mone; tI[93]=mone; tI[94]=mone;
    tI[95]=bfb(-sn);                     // spatial softmax shift (cancels)
  }
}

// ------------------------------------------------------------------- main ---
// Same 512-block grid shape as R8/R12/R13 (placement-proven: FETCH 14MB) but
// 1024-thread blocks: 16 waves = 8 row-groups x 2 j-half groups over the SAME
// jc chunk -> 2 blocks/CU x 16 waves = 32 waves/CU = 8 waves/SIMD (2x R13).
// No LDS merge (R11's failure point): each j-half writes its own partial set
// (16 sets; df_reduce<16> is the R4-proven path). Body = R12's exact 40-VGPR
// body; __launch_bounds__(1024,8) caps VGPR at 64 -> cannot spill at 40.
__global__ __launch_bounds__(1024, 8)
void df_main(const unsigned short* __restrict__ augI,
             const unsigned short* __restrict__ augJ,
             float* __restrict__ part)
{
  const int tid = threadIdx.x;
  const int wave = tid>>6, lane = tid&63;
  const int il = lane&31, hk = lane>>5;
  const int wl = wave&7, jh = wave>>3;   // row group, j-half group
  const int jc = blockIdx.x, it = blockIdx.y, b = blockIdx.z;

  const int irow = it*ITILE + wl*32 + il;
  const size_t ibase = ((size_t)(b*NPTS + irow))*AUGD;
  short8 bfr[6];
  #pragma unroll
  for (int s=0;s<6;s++)
    bfr[s] = *(const short8*)(augI + ibase + s*16 + hk*8);

  const unsigned short* jp =
      augJ + ((size_t)(b*NPTS + jc*JCH + jh*JHALF) + il)*AUGD + hk*8;

  float lP=0.f, sA=0.f, m=-1e30f, lQ=0.f, sB=0.f, sC=0.f;

  for (int t=0;t<NT;t++){
    short8 a[6];
    #pragma unroll
    for (int s=0;s<6;s++)
      a[s] = *(const short8*)(jp + s*16);   // 6x b128, imm offsets
    jp += (size_t)JT*AUGD;

    f32x16 z = {};
    f32x16 f0 = __builtin_amdgcn_mfma_f32_32x32x16_bf16(a[0], bfr[0], z, 0,0,0);
    f0 = __builtin_amdgcn_mfma_f32_32x32x16_bf16(a[1], bfr[1], f0,0,0,0);
    f0 = __builtin_amdgcn_mfma_f32_32x32x16_bf16(a[2], bfr[2], f0,0,0,0);
    f32x16 f1 = __builtin_amdgcn_mfma_f32_32x32x16_bf16(a[3], bfr[3], z,0,0,0);
    f1 = __builtin_amdgcn_mfma_f32_32x32x16_bf16(a[4], bfr[4], f1,0,0,0);
    f32x16 accS = __builtin_amdgcn_mfma_f32_32x32x16_bf16(a[5], bfr[5], z,0,0,0);
    f32x16 accF = f0 + f1;               // merge the two independent chains

    // tree max over accF (depth 4)
    float t0 = fmaxf(accF[0],accF[1]),  t1 = fmaxf(accF[2],accF[3]);
    float t2 = fmaxf(accF[4],accF[5]),  t3 = fmaxf(accF[6],accF[7]);
    float t4 = fmaxf(accF[8],accF[9]),  t5 = fmaxf(accF[10],accF[11]);
    float t6 = fmaxf(accF[12],accF[13]),t7 = fmaxf(accF[14],accF[15]);
    t0 = fmaxf(t0,t1); t2 = fmaxf(t2,t3); t4 = fmaxf(t4,t5); t6 = fmaxf(t6,t7);
    float tmax = fmaxf(fmaxf(t0,t2), fmaxf(t4,t6));

    if (!__all(tmax <= m)){              // defer-max: skip when no lane grew
      float mnew = fmaxf(m, tmax);
      float sg = fexp2(m - mnew);
      float sg2 = sg*sg;
      lQ *= sg; sB *= sg2; sC *= sg; m = mnew;
    }
    #pragma unroll
    for (int r=0;r<16;r++){
      float pv = fexp2(accS[r]);         // spatial shift pre-folded into MFMA
      float qv = fexp2(accF[r]-m);
      lP += pv;
      sA = fmaf(pv,pv,sA);
      lQ += qv;
      sB = fmaf(qv,qv,sB);
      sC = fmaf(pv,qv,sC);
    }
  }

  // merge the two hk-halves (disjoint j-subsets of same i-row) in-register
  float mo  = __shfl_xor(m, 32);
  float lPo = __shfl_xor(lP,32);
  float sAo = __shfl_xor(sA,32);
  float lQo = __shfl_xor(lQ,32);
  float sBo = __shfl_xor(sB,32);
  float sCo = __shfl_xor(sC,32);
  float mm = fmaxf(m, mo);
  float s0 = fexp2(m-mm), s1 = fexp2(mo-mm);
  lP += lPo; sA += sAo;
  lQ = lQ*s0 + lQo*s1;
  sB = sB*s0*s0 + sBo*s1*s1;
  sC = sC*s0 + sCo*s1;

  if (hk==0){
    const size_t pidx = (((size_t)(jc*2 + jh))*((size_t)BATCH*NPTS)
                         + (size_t)b*NPTS + irow)*8;
    float4 v0 = {lP, sA, mm, lQ};
    float4 v1 = {sB, sC, 0.f, 0.f};
    *(float4*)(part + pidx)     = v0;    // full 32B/row -> no partial lines
    *(float4*)(part + pidx + 4) = v1;
  }
}

// ----------------------------------------------------------------- reduce ---
template<int SETS>
__global__ void df_reduce(const float* __restrict__ part,
                          const float* __restrict__ w,
                          float* __restrict__ ws2)
{
  const int jb = blockIdx.x, b = blockIdx.y;
  const int tid = threadIdx.x;
  const int i = jb*256 + tid;
  const size_t stride = (size_t)BATCH*NPTS*8;
  const size_t base = ((size_t)b*NPTS + i)*8;
  float mx = -1e30f;
  #pragma unroll
  for (int k=0;k<SETS;k++)
    mx = fmaxf(mx, part[base + (size_t)k*stride + 2]);
  float lP=0,sA=0,lQ=0,sB=0,sC=0;
  #pragma unroll
  for (int k=0;k<SETS;k++){
    const float* pp = part + base + (size_t)k*stride;
    lP += pp[0]; sA += pp[1];
    float sg = fexp2(pp[2]-mx);
    lQ += sg*pp[3]; sB += sg*sg*pp[4]; sC += sg*pp[5];
  }
  float res = sA/(lP*lP) + sB/(lQ*lQ) - 2.0f*sC/(lP*lQ);
  float acc = w[(size_t)b*NPTS + i]*res;
  __shared__ float red[256];
  red[tid]=acc; __syncthreads();
  for (int s=128;s>0;s>>=1){
    if (tid<s) red[tid]+=red[tid+s];
    __syncthreads();
  }
  if (tid==0) ws2[b*16+jb]=red[0];
}

__global__ void df_final(const float* __restrict__ ws2, float* __restrict__ out){
  int b = threadIdx.x;
  if (b < BATCH){
    float s=0.f;
    #pragma unroll
    for (int k=0;k<16;k++) s += ws2[b*16+k];
    out[b]=s;
  }
}

// ----------------------------------------------------------------- launch ---
extern "C" void kernel_launch(void* const* d_in, const int* in_sizes, int n_in,
                              void* d_out, int out_size, void* d_ws, size_t ws_size,
                              hipStream_t stream) {
  const float* pts = (const float*)d_in[0];
  const float* w   = (const float*)d_in[1];
  const float* f1  = (const float*)d_in[2];
  const float* f2  = (const float*)d_in[3];
  float* out = (float*)d_out;

  unsigned char* ws = (unsigned char*)d_ws;
  const size_t AUG_BYTES = (size_t)BATCH*NPTS*AUGD*2;        // 3,145,728
  unsigned short* augI = (unsigned short*)(ws);
  unsigned short* augJ = (unsigned short*)(ws + AUG_BYTES);
  float* part = (float*)(ws + 2*AUG_BYTES);

  const size_t PART16 = (size_t)16*BATCH*NPTS*8*4;           // 8,388,608
  float* ws2 = (float*)(ws + 2*AUG_BYTES + PART16);

  df_prep<<<(BATCH*NPTS)/4, 256, 0, stream>>>(pts, f1, f2, augI, augJ);
  df_main<<<dim3(JSPLIT, NPTS/ITILE, BATCH), 1024, 0, stream>>>(augI, augJ, part);
  df_reduce<16><<<dim3(16, BATCH), 256, 0, stream>>>(part, w, ws2);
  df_final<<<1, 64, 0, stream>>>(ws2, out);
}

// Round 15
// 52.553 us; speedup vs baseline: 1.3476x; 1.3476x over previous
//
#include <hip/hip_runtime.h>

#define BATCH 4
#define NPTS 4096
#define DF 64
#define ITILE 256              // 8 waves x 32 rows
#define JSPLIT 8
#define JCH (NPTS/JSPLIT)      // 512
#define JT 32
#define NT (JCH/JT)            // 16 (even)
#define AUGD 96                // 80 feature (5x K16) + 16 spatial (1x K16)
#define TPB 128                // j-tiles per batch (4096/32)
#define TILEU 3072             // ushorts per packed tile (6 slices x 512)
#define LOG2E 1.4426950408889634f

typedef short short8 __attribute__((ext_vector_type(8)));
typedef float f32x16 __attribute__((ext_vector_type(16)));

__device__ __forceinline__ unsigned short bfb(float x){
  unsigned int u = __float_as_uint(x);
  u += 0x7FFFu + ((u>>16)&1u);          // RNE
  return (unsigned short)(u>>16);
}
__device__ __forceinline__ float bff(unsigned short h){
  return __uint_as_float(((unsigned int)h)<<16);
}
__device__ __forceinline__ float fexp2(float x){   // raw v_exp_f32 (2^x)
  float r; asm("v_exp_f32 %0, %1" : "=v"(r) : "v"(x)); return r;
}

// Packed-tile address (in ushorts) for element col c of j-row jj, batch b:
// tile T=jj>>5, row r=jj&31, slice s=c>>4, k-half h=(c>>3)&1, elem e=c&7.
// Layout [b][T][s][h*32+r][e]: a wave's fragment-load s is ONE contiguous
// 1KB block (lane l reads chunk h*32+r with r=l&31,h=l>>5 — the exact
// mfma_32x32x16 A-fragment lane mapping, validated absmax 0.0 R9-R14).
__device__ __forceinline__ size_t jaddr(int b, int jj, int c){
  int T = jj>>5, r = jj&31;
  int s = c>>4, h = (c>>3)&1, e = c&7;
  return ((size_t)(b*TPB + T))*TILEU + s*512 + (h*32 + r)*8 + e;
}

// ---------------------------------------------------------------- prepass ---
// Same math as R12-R14 (validated): log2-domain scores fully folded into MFMA.
//  accF = log2e*(2*f1.f2 - |f2|^2)
//  accS = log2e*(2*xs_i.xs_j - |xs_j|^2) - bf16(log2e*|xs_i|^2)
// Only the augJ STORAGE layout changed (tile-major packing for coalescing).
__global__ void df_prep(const float* __restrict__ pts,
                        const float* __restrict__ f1,
                        const float* __restrict__ f2,
                        unsigned short* __restrict__ augI,
                        unsigned short* __restrict__ augJ)
{
  int wid = (blockIdx.x<<2) + (threadIdx.x>>6);
  int lane = threadIdx.x & 63;
  if (wid >= BATCH*NPTS) return;
  const int b = wid>>12, jj = wid&4095;
  float v1 = f1[(size_t)wid*DF + lane];
  float v2 = f2[(size_t)wid*DF + lane];
  float r2 = v2*v2;
  #pragma unroll
  for (int s=32;s>=1;s>>=1)
    r2 += __shfl_xor(r2, s);
  augI[(size_t)wid*AUGD + lane] = bfb(2.0f*LOG2E*v1);
  augJ[jaddr(b, jj, lane)] = bfb(v2);
  if (lane==0){
    float px = pts[(size_t)wid*3+0]/0.05f;
    float py = pts[(size_t)wid*3+1]/0.05f;
    float pz = pts[(size_t)wid*3+2]/0.05f;
    float nss = px*px+py*py+pz*pz;
    unsigned short* tI = augI + (size_t)wid*AUGD;
    float fn = LOG2E*r2;
    unsigned short a0 = bfb(fn); float rem = fn - bff(a0);
    unsigned short a1 = bfb(rem); rem -= bff(a1);
    unsigned short a2 = bfb(rem);
    augJ[jaddr(b,jj,64)]=a0; augJ[jaddr(b,jj,65)]=a1; augJ[jaddr(b,jj,66)]=a2;
    #pragma unroll
    for (int k=67;k<80;k++) augJ[jaddr(b,jj,k)]=0;
    unsigned short hx=bfb(px), hy=bfb(py), hz=bfb(pz);
    float lx = px-bff(hx), ly = py-bff(hy), lz = pz-bff(hz);
    unsigned short lxb=bfb(lx), lyb=bfb(ly), lzb=bfb(lz);
    augJ[jaddr(b,jj,80)]=hx; augJ[jaddr(b,jj,81)]=hy; augJ[jaddr(b,jj,82)]=hz;
    augJ[jaddr(b,jj,83)]=lxb;augJ[jaddr(b,jj,84)]=lyb;augJ[jaddr(b,jj,85)]=lzb;
    augJ[jaddr(b,jj,86)]=hx; augJ[jaddr(b,jj,87)]=hy; augJ[jaddr(b,jj,88)]=hz;
    augJ[jaddr(b,jj,89)]=lxb;augJ[jaddr(b,jj,90)]=lyb;augJ[jaddr(b,jj,91)]=lzb;
    float sn = LOG2E*nss;
    a0 = bfb(sn); rem = sn - bff(a0);
    a1 = bfb(rem); rem -= bff(a1);
    a2 = bfb(rem);
    augJ[jaddr(b,jj,92)]=a0; augJ[jaddr(b,jj,93)]=a1; augJ[jaddr(b,jj,94)]=a2;
    augJ[jaddr(b,jj,95)]=bfb(1.0f);      // exact 1.0: carries -sn_i shift
    unsigned short mone = bfb(-1.0f);
    tI[64]=mone; tI[65]=mone; tI[66]=mone;
    #pragma unroll
    for (int k=67;k<80;k++) tI[k]=0;
    float sx = 2.f*LOG2E*px, sy = 2.f*LOG2E*py, sz = 2.f*LOG2E*pz;
    unsigned short h2x=bfb(sx), h2y=bfb(sy), h2z=bfb(sz);
    float l2xf = sx-bff(h2x), l2yf = sy-bff(h2y), l2zf = sz-bff(h2z);
    unsigned short l2x=bfb(l2xf), l2y=bfb(l2yf), l2z=bfb(l2zf);
    tI[80]=h2x; tI[81]=h2y; tI[82]=h2z;
    tI[83]=h2x; tI[84]=h2y; tI[85]=h2z;
    tI[86]=l2x; tI[87]=l2y; tI[88]=l2z;
    tI[89]=l2x; tI[90]=l2y; tI[91]=l2z;
    tI[92]=mone; tI[93]=mone; tI[94]=mone;
    tI[95]=bfb(-sn);                     // spatial softmax shift (cancels)
  }
}

// ------------------------------------------------------------------- main ---
// R13 structure (512x512 grid x=jc proven FETCH 14MB; named-reg double
// buffer; launch_bounds(512,2) no-spill) + COALESCED j-loads: packed tiles
// make each fragment load one contiguous 1KB block -> 16 full-line requests
// instead of 32 half-line ones (halves L1 request pressure, the R14-derived
// bottleneck theory).

#define LOAD6I(p, v0,v1,v2,v3,v4,v5)                 \
  v0 = *(const short8*)(p);                          \
  v1 = *(const short8*)((p)+16);                     \
  v2 = *(const short8*)((p)+32);                     \
  v3 = *(const short8*)((p)+48);                     \
  v4 = *(const short8*)((p)+64);                     \
  v5 = *(const short8*)((p)+80);

#define LOAD6J(p, v0,v1,v2,v3,v4,v5)                 \
  v0 = *(const short8*)(p);                          \
  v1 = *(const short8*)((p)+512);                    \
  v2 = *(const short8*)((p)+1024);                   \
  v3 = *(const short8*)((p)+1536);                   \
  v4 = *(const short8*)((p)+2048);                   \
  v5 = *(const short8*)((p)+2560);

#define MFMA_BF16 __builtin_amdgcn_mfma_f32_32x32x16_bf16

#define TILE_BODY(v0,v1,v2,v3,v4,v5, PRELOAD)                            \
  {                                                                      \
    f32x16 z = {};                                                       \
    f32x16 f0 = MFMA_BF16(v0, bfr0, z, 0,0,0);                           \
    f0 = MFMA_BF16(v1, bfr1, f0,0,0,0);                                  \
    f0 = MFMA_BF16(v2, bfr2, f0,0,0,0);                                  \
    f32x16 f1 = MFMA_BF16(v3, bfr3, z,0,0,0);                            \
    f1 = MFMA_BF16(v4, bfr4, f1,0,0,0);                                  \
    f32x16 accS = MFMA_BF16(v5, bfr5, z,0,0,0);                          \
    PRELOAD                                                              \
    f32x16 accF = f0 + f1;                                               \
    float t0 = fmaxf(accF[0],accF[1]),  t1 = fmaxf(accF[2],accF[3]);     \
    float t2 = fmaxf(accF[4],accF[5]),  t3 = fmaxf(accF[6],accF[7]);     \
    float t4 = fmaxf(accF[8],accF[9]),  t5 = fmaxf(accF[10],accF[11]);   \
    float t6 = fmaxf(accF[12],accF[13]),t7 = fmaxf(accF[14],accF[15]);   \
    t0 = fmaxf(t0,t1); t2 = fmaxf(t2,t3);                                \
    t4 = fmaxf(t4,t5); t6 = fmaxf(t6,t7);                                \
    float tmax = fmaxf(fmaxf(t0,t2), fmaxf(t4,t6));                      \
    if (!__all(tmax <= m)){                                              \
      float mnew = fmaxf(m, tmax);                                       \
      float sg = fexp2(m - mnew);                                        \
      float sg2 = sg*sg;                                                 \
      lQ *= sg; sB *= sg2; sC *= sg; m = mnew;                           \
    }                                                                    \
    _Pragma("unroll")                                                    \
    for (int r=0;r<16;r++){                                              \
      float pv = fexp2(accS[r]);                                         \
      float qv = fexp2(accF[r]-m);                                       \
      lP += pv;                                                          \
      sA = fmaf(pv,pv,sA);                                               \
      lQ += qv;                                                          \
      sB = fmaf(qv,qv,sB);                                               \
      sC = fmaf(pv,qv,sC);                                               \
    }                                                                    \
  }

__global__ __launch_bounds__(512, 2)
void df_main(const unsigned short* __restrict__ augI,
             const unsigned short* __restrict__ augJ,
             float* __restrict__ part)
{
  const int tid = threadIdx.x;
  const int wave = tid>>6, lane = tid&63;
  const int il = lane&31, hk = lane>>5;
  const int jc = blockIdx.x, it = blockIdx.y, b = blockIdx.z;

  const int irow = it*ITILE + wave*32 + il;
  const size_t ibase = ((size_t)(b*NPTS + irow))*AUGD;
  short8 bfr0,bfr1,bfr2,bfr3,bfr4,bfr5;
  LOAD6I(augI + ibase + hk*8, bfr0,bfr1,bfr2,bfr3,bfr4,bfr5)

  // packed-tile pointer: lane's 16B chunk within each 1KB slice block
  const unsigned short* jp =
      augJ + ((size_t)(b*TPB + jc*NT))*TILEU + lane*8;
  const size_t step = TILEU;             // 3072 ushorts per tile

  float lP=0.f, sA=0.f, m=-1e30f, lQ=0.f, sB=0.f, sC=0.f;

  short8 xa0,xa1,xa2,xa3,xa4,xa5;        // buffer A (even tiles)
  short8 xb0,xb1,xb2,xb3,xb4,xb5;        // buffer B (odd tiles)
  LOAD6J(jp,        xa0,xa1,xa2,xa3,xa4,xa5)   // t = 0
  LOAD6J(jp + step, xb0,xb1,xb2,xb3,xb4,xb5)   // t = 1
  const unsigned short* jpf = jp + 2*step;     // next to fetch: t = 2

  for (int t=0; t<NT; t+=2){
    TILE_BODY(xa0,xa1,xa2,xa3,xa4,xa5,
      if (t+2 < NT){
        LOAD6J(jpf, xa0,xa1,xa2,xa3,xa4,xa5)   // prefetch t+2 into dead A
        jpf += step;
      })
    TILE_BODY(xb0,xb1,xb2,xb3,xb4,xb5,
      if (t+3 < NT){
        LOAD6J(jpf, xb0,xb1,xb2,xb3,xb4,xb5)   // prefetch t+3 into dead B
        jpf += step;
      })
  }

  // merge the two hk-halves (disjoint j-subsets of same i-row) in-register
  float mo  = __shfl_xor(m, 32);
  float lPo = __shfl_xor(lP,32);
  float sAo = __shfl_xor(sA,32);
  float lQo = __shfl_xor(lQ,32);
  float sBo = __shfl_xor(sB,32);
  float sCo = __shfl_xor(sC,32);
  float mm = fmaxf(m, mo);
  float s0 = fexp2(m-mm), s1 = fexp2(mo-mm);
  lP += lPo; sA += sAo;
  lQ = lQ*s0 + lQo*s1;
  sB = sB*s0*s0 + sBo*s1*s1;
  sC = sC*s0 + sCo*s1;

  if (hk==0){
    const size_t pidx = (((size_t)jc)*((size_t)BATCH*NPTS)
                         + (size_t)b*NPTS + irow)*8;
    float4 v0 = {lP, sA, mm, lQ};
    float4 v1 = {sB, sC, 0.f, 0.f};
    *(float4*)(part + pidx)     = v0;    // full 32B/row -> no partial lines
    *(float4*)(part + pidx + 4) = v1;
  }
}

// ----------------------------------------------------------------- reduce ---
template<int SETS>
__global__ void df_reduce(const float* __restrict__ part,
                          const float* __restrict__ w,
                          float* __restrict__ ws2)
{
  const int jb = blockIdx.x, b = blockIdx.y;
  const int tid = threadIdx.x;
  const int i = jb*256 + tid;
  const size_t stride = (size_t)BATCH*NPTS*8;
  const size_t base = ((size_t)b*NPTS + i)*8;
  float mx = -1e30f;
  #pragma unroll
  for (int k=0;k<SETS;k++)
    mx = fmaxf(mx, part[base + (size_t)k*stride + 2]);
  float lP=0,sA=0,lQ=0,sB=0,sC=0;
  #pragma unroll
  for (int k=0;k<SETS;k++){
    const float* pp = part + base + (size_t)k*stride;
    lP += pp[0]; sA += pp[1];
    float sg = fexp2(pp[2]-mx);
    lQ += sg*pp[3]; sB += sg*sg*pp[4]; sC += sg*pp[5];
  }
  float res = sA/(lP*lP) + sB/(lQ*lQ) - 2.0f*sC/(lP*lQ);
  float acc = w[(size_t)b*NPTS + i]*res;
  __shared__ float red[256];
  red[tid]=acc; __syncthreads();
  for (int s=128;s>0;s>>=1){
    if (tid<s) red[tid]+=red[tid+s];
    __syncthreads();
  }
  if (tid==0) ws2[b*16+jb]=red[0];
}

__global__ void df_final(const float* __restrict__ ws2, float* __restrict__ out){
  int b = threadIdx.x;
  if (b < BATCH){
    float s=0.f;
    #pragma unroll
    for (int k=0;k<16;k++) s += ws2[b*16+k];
    out[b]=s;
  }
}

// ----------------------------------------------------------------- launch ---
extern "C" void kernel_launch(void* const* d_in, const int* in_sizes, int n_in,
                              void* d_out, int out_size, void* d_ws, size_t ws_size,
                              hipStream_t stream) {
  const float* pts = (const float*)d_in[0];
  const float* w   = (const float*)d_in[1];
  const float* f1  = (const float*)d_in[2];
  const float* f2  = (const float*)d_in[3];
  float* out = (float*)d_out;

  unsigned char* ws = (unsigned char*)d_ws;
  const size_t AUG_BYTES = (size_t)BATCH*NPTS*AUGD*2;        // 3,145,728 each
  unsigned short* augI = (unsigned short*)(ws);
  unsigned short* augJ = (unsigned short*)(ws + AUG_BYTES);
  float* part = (float*)(ws + 2*AUG_BYTES);

  const size_t PART8 = (size_t)JSPLIT*BATCH*NPTS*8*4;        // 4,194,304
  float* ws2 = (float*)(ws + 2*AUG_BYTES + PART8);

  df_prep<<<(BATCH*NPTS)/4, 256, 0, stream>>>(pts, f1, f2, augI, augJ);
  df_main<<<dim3(JSPLIT, NPTS/ITILE, BATCH), 512, 0, stream>>>(augI, augJ, part);
  df_reduce<JSPLIT><<<dim3(16, BATCH), 256, 0, stream>>>(part, w, ws2);
  df_final<<<1, 64, 0, stream>>>(ws2, out);
}

// Round 16
// 52.125 us; speedup vs baseline: 1.3586x; 1.0082x over previous
//
#include <hip/hip_runtime.h>

#define BATCH 4
#define NPTS 4096
#define DF 64
#define ITILE 256              // 8 waves x 32 rows
#define JSPLIT 8
#define JCH (NPTS/JSPLIT)      // 512
#define JT 32
#define NT (JCH/JT)            // 16 (even)
#define AUGD 96                // 80 feature (5x K16) + 16 spatial (1x K16)
#define TPB 128                // j-tiles per batch (4096/32)
#define TILEU 3072             // ushorts per packed tile (6 slices x 512)
#define LOG2E 1.4426950408889634f

typedef short short8 __attribute__((ext_vector_type(8)));
typedef float f32x16 __attribute__((ext_vector_type(16)));

__device__ __forceinline__ unsigned short bfb(float x){
  unsigned int u = __float_as_uint(x);
  u += 0x7FFFu + ((u>>16)&1u);          // RNE
  return (unsigned short)(u>>16);
}
__device__ __forceinline__ float bff(unsigned short h){
  return __uint_as_float(((unsigned int)h)<<16);
}
__device__ __forceinline__ float fexp2(float x){   // raw v_exp_f32 (2^x)
  float r; asm("v_exp_f32 %0, %1" : "=v"(r) : "v"(x)); return r;
}

// Packed-tile address (in ushorts) for element col c of j-row jj, batch b.
// Layout [b][T][s][h*32+r][e]: a wave's fragment-load s is ONE contiguous
// 1KB block (lane l reads chunk h*32+r with r=l&31,h=l>>5 — the exact
// mfma_32x32x16 A-fragment lane mapping; validated absmax 0.0 R15).
__device__ __forceinline__ size_t jaddr(int b, int jj, int c){
  int T = jj>>5, r = jj&31;
  int s = c>>4, h = (c>>3)&1, e = c&7;
  return ((size_t)(b*TPB + T))*TILEU + s*512 + (h*32 + r)*8 + e;
}

// ---------------------------------------------------------------- prepass ---
// UNCHANGED from R15 (validated, absmax 0.0). Log2-domain scores fully
// folded into the MFMA; augJ stored tile-major (coalesced fragment loads).
__global__ void df_prep(const float* __restrict__ pts,
                        const float* __restrict__ f1,
                        const float* __restrict__ f2,
                        unsigned short* __restrict__ augI,
                        unsigned short* __restrict__ augJ)
{
  int wid = (blockIdx.x<<2) + (threadIdx.x>>6);
  int lane = threadIdx.x & 63;
  if (wid >= BATCH*NPTS) return;
  const int b = wid>>12, jj = wid&4095;
  float v1 = f1[(size_t)wid*DF + lane];
  float v2 = f2[(size_t)wid*DF + lane];
  float r2 = v2*v2;
  #pragma unroll
  for (int s=32;s>=1;s>>=1)
    r2 += __shfl_xor(r2, s);
  augI[(size_t)wid*AUGD + lane] = bfb(2.0f*LOG2E*v1);
  augJ[jaddr(b, jj, lane)] = bfb(v2);
  if (lane==0){
    float px = pts[(size_t)wid*3+0]/0.05f;
    float py = pts[(size_t)wid*3+1]/0.05f;
    float pz = pts[(size_t)wid*3+2]/0.05f;
    float nss = px*px+py*py+pz*pz;
    unsigned short* tI = augI + (size_t)wid*AUGD;
    float fn = LOG2E*r2;
    unsigned short a0 = bfb(fn); float rem = fn - bff(a0);
    unsigned short a1 = bfb(rem); rem -= bff(a1);
    unsigned short a2 = bfb(rem);
    augJ[jaddr(b,jj,64)]=a0; augJ[jaddr(b,jj,65)]=a1; augJ[jaddr(b,jj,66)]=a2;
    #pragma unroll
    for (int k=67;k<80;k++) augJ[jaddr(b,jj,k)]=0;
    unsigned short hx=bfb(px), hy=bfb(py), hz=bfb(pz);
    float lx = px-bff(hx), ly = py-bff(hy), lz = pz-bff(hz);
    unsigned short lxb=bfb(lx), lyb=bfb(ly), lzb=bfb(lz);
    augJ[jaddr(b,jj,80)]=hx; augJ[jaddr(b,jj,81)]=hy; augJ[jaddr(b,jj,82)]=hz;
    augJ[jaddr(b,jj,83)]=lxb;augJ[jaddr(b,jj,84)]=lyb;augJ[jaddr(b,jj,85)]=lzb;
    augJ[jaddr(b,jj,86)]=hx; augJ[jaddr(b,jj,87)]=hy; augJ[jaddr(b,jj,88)]=hz;
    augJ[jaddr(b,jj,89)]=lxb;augJ[jaddr(b,jj,90)]=lyb;augJ[jaddr(b,jj,91)]=lzb;
    float sn = LOG2E*nss;
    a0 = bfb(sn); rem = sn - bff(a0);
    a1 = bfb(rem); rem -= bff(a1);
    a2 = bfb(rem);
    augJ[jaddr(b,jj,92)]=a0; augJ[jaddr(b,jj,93)]=a1; augJ[jaddr(b,jj,94)]=a2;
    augJ[jaddr(b,jj,95)]=bfb(1.0f);      // exact 1.0: carries -sn_i shift
    unsigned short mone = bfb(-1.0f);
    tI[64]=mone; tI[65]=mone; tI[66]=mone;
    #pragma unroll
    for (int k=67;k<80;k++) tI[k]=0;
    float sx = 2.f*LOG2E*px, sy = 2.f*LOG2E*py, sz = 2.f*LOG2E*pz;
    unsigned short h2x=bfb(sx), h2y=bfb(sy), h2z=bfb(sz);
    float l2xf = sx-bff(h2x), l2yf = sy-bff(h2y), l2zf = sz-bff(h2z);
    unsigned short l2x=bfb(l2xf), l2y=bfb(l2yf), l2z=bfb(l2zf);
    tI[80]=h2x; tI[81]=h2y; tI[82]=h2z;
    tI[83]=h2x; tI[84]=h2y; tI[85]=h2z;
    tI[86]=l2x; tI[87]=l2y; tI[88]=l2z;
    tI[89]=l2x; tI[90]=l2y; tI[91]=l2z;
    tI[92]=mone; tI[93]=mone; tI[94]=mone;
    tI[95]=bfb(-sn);                     // spatial softmax shift (cancels)
  }
}

// ------------------------------------------------------------------- main ---
// R15 structure (512x512 grid x=jc: FETCH 14MB; packed coalesced j-loads;
// named-reg double buffer; launch_bounds(512,2) no-spill) + INDEPENDENT
// ACCUMULATOR STREAMS: even tiles -> {m0,...}, odd tiles -> {m1,...}, merged
// once at the end (exact exponent-rebase, disjoint j-partitions). The even
// and odd tile bodies then share nothing writable -> the scheduler can
// overlap body B's loads/MFMAs/exps into body A's ~850cy stall shadow
// (ILP x2 without TLP (R14 regressed) or extra buffers (R9/R10 spilled)).

#define LOAD6I(p, v0,v1,v2,v3,v4,v5)                 \
  v0 = *(const short8*)(p);                          \
  v1 = *(const short8*)((p)+16);                     \
  v2 = *(const short8*)((p)+32);                     \
  v3 = *(const short8*)((p)+48);                     \
  v4 = *(const short8*)((p)+64);                     \
  v5 = *(const short8*)((p)+80);

#define LOAD6J(p, v0,v1,v2,v3,v4,v5)                 \
  v0 = *(const short8*)(p);                          \
  v1 = *(const short8*)((p)+512);                    \
  v2 = *(const short8*)((p)+1024);                   \
  v3 = *(const short8*)((p)+1536);                   \
  v4 = *(const short8*)((p)+2048);                   \
  v5 = *(const short8*)((p)+2560);

#define MFMA_BF16 __builtin_amdgcn_mfma_f32_32x32x16_bf16

#define TILE_BODY(v0,v1,v2,v3,v4,v5, M,LP,SA,LQ,SB,SC, PRELOAD)          \
  {                                                                      \
    f32x16 z = {};                                                       \
    f32x16 f0 = MFMA_BF16(v0, bfr0, z, 0,0,0);                           \
    f0 = MFMA_BF16(v1, bfr1, f0,0,0,0);                                  \
    f0 = MFMA_BF16(v2, bfr2, f0,0,0,0);                                  \
    f32x16 f1 = MFMA_BF16(v3, bfr3, z,0,0,0);                            \
    f1 = MFMA_BF16(v4, bfr4, f1,0,0,0);                                  \
    f32x16 accS = MFMA_BF16(v5, bfr5, z,0,0,0);                          \
    PRELOAD                                                              \
    f32x16 accF = f0 + f1;                                               \
    float t0 = fmaxf(accF[0],accF[1]),  t1 = fmaxf(accF[2],accF[3]);     \
    float t2 = fmaxf(accF[4],accF[5]),  t3 = fmaxf(accF[6],accF[7]);     \
    float t4 = fmaxf(accF[8],accF[9]),  t5 = fmaxf(accF[10],accF[11]);   \
    float t6 = fmaxf(accF[12],accF[13]),t7 = fmaxf(accF[14],accF[15]);   \
    t0 = fmaxf(t0,t1); t2 = fmaxf(t2,t3);                                \
    t4 = fmaxf(t4,t5); t6 = fmaxf(t6,t7);                                \
    float tmax = fmaxf(fmaxf(t0,t2), fmaxf(t4,t6));                      \
    if (!__all(tmax <= M)){                                              \
      float mnew = fmaxf(M, tmax);                                       \
      float sg = fexp2(M - mnew);                                        \
      float sg2 = sg*sg;                                                 \
      LQ *= sg; SB *= sg2; SC *= sg; M = mnew;                           \
    }                                                                    \
    _Pragma("unroll")                                                    \
    for (int r=0;r<16;r++){                                              \
      float pv = fexp2(accS[r]);                                         \
      float qv = fexp2(accF[r]-M);                                       \
      LP += pv;                                                          \
      SA = fmaf(pv,pv,SA);                                               \
      LQ += qv;                                                          \
      SB = fmaf(qv,qv,SB);                                               \
      SC = fmaf(pv,qv,SC);                                               \
    }                                                                    \
  }

__global__ __launch_bounds__(512, 2)
void df_main(const unsigned short* __restrict__ augI,
             const unsigned short* __restrict__ augJ,
             float* __restrict__ part)
{
  const int tid = threadIdx.x;
  const int wave = tid>>6, lane = tid&63;
  const int il = lane&31, hk = lane>>5;
  const int jc = blockIdx.x, it = blockIdx.y, b = blockIdx.z;

  const int irow = it*ITILE + wave*32 + il;
  const size_t ibase = ((size_t)(b*NPTS + irow))*AUGD;
  short8 bfr0,bfr1,bfr2,bfr3,bfr4,bfr5;
  LOAD6I(augI + ibase + hk*8, bfr0,bfr1,bfr2,bfr3,bfr4,bfr5)

  // packed-tile pointer: lane's 16B chunk within each 1KB slice block
  const unsigned short* jp =
      augJ + ((size_t)(b*TPB + jc*NT))*TILEU + lane*8;
  const size_t step = TILEU;             // 3072 ushorts per tile

  // stream 0: even tiles; stream 1: odd tiles (independent -> ILP x2)
  float lP0=0.f, sA0=0.f, m0=-1e30f, lQ0=0.f, sB0=0.f, sC0=0.f;
  float lP1=0.f, sA1=0.f, m1=-1e30f, lQ1=0.f, sB1=0.f, sC1=0.f;

  short8 xa0,xa1,xa2,xa3,xa4,xa5;        // buffer A (even tiles)
  short8 xb0,xb1,xb2,xb3,xb4,xb5;        // buffer B (odd tiles)
  LOAD6J(jp,        xa0,xa1,xa2,xa3,xa4,xa5)   // t = 0
  LOAD6J(jp + step, xb0,xb1,xb2,xb3,xb4,xb5)   // t = 1
  const unsigned short* jpf = jp + 2*step;     // next to fetch: t = 2

  for (int t=0; t<NT; t+=2){
    TILE_BODY(xa0,xa1,xa2,xa3,xa4,xa5, m0,lP0,sA0,lQ0,sB0,sC0,
      if (t+2 < NT){
        LOAD6J(jpf, xa0,xa1,xa2,xa3,xa4,xa5)   // prefetch t+2 into dead A
        jpf += step;
      })
    TILE_BODY(xb0,xb1,xb2,xb3,xb4,xb5, m1,lP1,sA1,lQ1,sB1,sC1,
      if (t+3 < NT){
        LOAD6J(jpf, xb0,xb1,xb2,xb3,xb4,xb5)   // prefetch t+3 into dead B
        jpf += step;
      })
  }

  // merge stream 1 into stream 0 (disjoint j-subsets; exact rebase)
  float mS = fmaxf(m0, m1);
  float e0 = fexp2(m0-mS), e1 = fexp2(m1-mS);
  float lP = lP0 + lP1;
  float sA = sA0 + sA1;
  float lQ = lQ0*e0 + lQ1*e1;
  float sB = sB0*e0*e0 + sB1*e1*e1;
  float sC = sC0*e0 + sC1*e1;
  float m  = mS;

  // merge the two hk-halves (disjoint j-subsets of same i-row) in-register
  float mo  = __shfl_xor(m, 32);
  float lPo = __shfl_xor(lP,32);
  float sAo = __shfl_xor(sA,32);
  float lQo = __shfl_xor(lQ,32);
  float sBo = __shfl_xor(sB,32);
  float sCo = __shfl_xor(sC,32);
  float mm = fmaxf(m, mo);
  float s0 = fexp2(m-mm), s1 = fexp2(mo-mm);
  lP += lPo; sA += sAo;
  lQ = lQ*s0 + lQo*s1;
  sB = sB*s0*s0 + sBo*s1*s1;
  sC = sC*s0 + sCo*s1;

  if (hk==0){
    const size_t pidx = (((size_t)jc)*((size_t)BATCH*NPTS)
                         + (size_t)b*NPTS + irow)*8;
    float4 v0 = {lP, sA, mm, lQ};
    float4 v1 = {sB, sC, 0.f, 0.f};
    *(float4*)(part + pidx)     = v0;    // full 32B/row -> no partial lines
    *(float4*)(part + pidx + 4) = v1;
  }
}

// ----------------------------------------------------------------- reduce ---
template<int SETS>
__global__ void df_reduce(const float* __restrict__ part,
                          const float* __restrict__ w,
                          float* __restrict__ ws2)
{
  const int jb = blockIdx.x, b = blockIdx.y;
  const int tid = threadIdx.x;
  const int i = jb*256 + tid;
  const size_t stride = (size_t)BATCH*NPTS*8;
  const size_t base = ((size_t)b*NPTS + i)*8;
  float mx = -1e30f;
  #pragma unroll
  for (int k=0;k<SETS;k++)
    mx = fmaxf(mx, part[base + (size_t)k*stride + 2]);
  float lP=0,sA=0,lQ=0,sB=0,sC=0;
  #pragma unroll
  for (int k=0;k<SETS;k++){
    const float* pp = part + base + (size_t)k*stride;
    lP += pp[0]; sA += pp[1];
    float sg = fexp2(pp[2]-mx);
    lQ += sg*pp[3]; sB += sg*sg*pp[4]; sC += sg*pp[5];
  }
  float res = sA/(lP*lP) + sB/(lQ*lQ) - 2.0f*sC/(lP*lQ);
  float acc = w[(size_t)b*NPTS + i]*res;
  __shared__ float red[256];
  red[tid]=acc; __syncthreads();
  for (int s=128;s>0;s>>=1){
    if (tid<s) red[tid]+=red[tid+s];
    __syncthreads();
  }
  if (tid==0) ws2[b*16+jb]=red[0];
}

__global__ void df_final(const float* __restrict__ ws2, float* __restrict__ out){
  int b = threadIdx.x;
  if (b < BATCH){
    float s=0.f;
    #pragma unroll
    for (int k=0;k<16;k++) s += ws2[b*16+k];
    out[b]=s;
  }
}

// ----------------------------------------------------------------- launch ---
extern "C" void kernel_launch(void* const* d_in, const int* in_sizes, int n_in,
                              void* d_out, int out_size, void* d_ws, size_t ws_size,
                              hipStream_t stream) {
  const float* pts = (const float*)d_in[0];
  const float* w   = (const float*)d_in[1];
  const float* f1  = (const float*)d_in[2];
  const float* f2  = (const float*)d_in[3];
  float* out = (float*)d_out;

  unsigned char* ws = (unsigned char*)d_ws;
  const size_t AUG_BYTES = (size_t)BATCH*NPTS*AUGD*2;        // 3,145,728 each
  unsigned short* augI = (unsigned short*)(ws);
  unsigned short* augJ = (unsigned short*)(ws + AUG_BYTES);
  float* part = (float*)(ws + 2*AUG_BYTES);

  const size_t PART8 = (size_t)JSPLIT*BATCH*NPTS*8*4;        // 4,194,304
  float* ws2 = (float*)(ws + 2*AUG_BYTES + PART8);

  df_prep<<<(BATCH*NPTS)/4, 256, 0, stream>>>(pts, f1, f2, augI, augJ);
  df_main<<<dim3(JSPLIT, NPTS/ITILE, BATCH), 512, 0, stream>>>(augI, augJ, part);
  df_reduce<JSPLIT><<<dim3(16, BATCH), 256, 0, stream>>>(part, w, ws2);
  df_final<<<1, 64, 0, stream>>>(ws2, out);
}